// Round 3
// baseline (355.815 us; speedup 1.0000x reference)
//
#include <hip/hip_runtime.h>
#include <hip/hip_bf16.h>
#include <stdint.h>

#define B_ 8
#define L_ 2048
#define D_ 256

typedef unsigned short u16;
typedef __attribute__((ext_vector_type(4))) float f32x4;
typedef __attribute__((ext_vector_type(8))) short bf16x8;

__device__ __forceinline__ u16 f2b(float f) {
  union { float f; unsigned u; } v; v.f = f;
  unsigned r = v.u + 0x7FFFu + ((v.u >> 16) & 1u);
  return (u16)(r >> 16);
}

__device__ __forceinline__ float b2f(u16 u) {
  union { unsigned u; float f; } v; v.u = ((unsigned)u) << 16;
  return v.f;
}

__device__ __forceinline__ void comb(float& m, float& s, float m2, float s2) {
  float mn = fmaxf(m, m2);
  s = s * __expf(m - mn) + s2 * __expf(m2 - mn);
  m = mn;
}

__device__ __forceinline__ void async_copy16(const void* g, u16* l) {
  __builtin_amdgcn_global_load_lds(
      (const __attribute__((address_space(1))) unsigned*)g,
      (__attribute__((address_space(3))) unsigned*)l,
      16, 0, 0);
}

// ---- shared GEMM core: C[128x128] tile, A[M,K]·B[N,K]^T, K contiguous ----
template<int KD>
__device__ __forceinline__ void gemm_core(const u16* __restrict__ Ag,
                                          const u16* __restrict__ Bg,
                                          int tile_m, int tile_n,
                                          u16* lds_a, u16* lds_b,
                                          f32x4 acc[4][4]) {
  const int tid  = threadIdx.x;
  const int wave = tid >> 6, lane = tid & 63;
  const int qd = lane >> 4, ln = lane & 15;
  const int wm = wave >> 1, wn = wave & 1;
  const int lrow = lane >> 2;         // 0..15
  const int lcol = (lane & 3) * 8;    // element offset (16B chunks)
  const u16* Abase = Ag + (size_t)tile_m * KD + lcol;
  const u16* Bbase = Bg + (size_t)tile_n * KD + lcol;

  for (int k0 = 0; k0 < KD; k0 += 32) {
#pragma unroll
    for (int j = 0; j < 2; ++j) {
      const int r0 = j * 64 + wave * 16;   // wave-uniform
      async_copy16(Abase + (size_t)(r0 + lrow) * KD + k0, lds_a + r0 * 32);
      async_copy16(Bbase + (size_t)(r0 + lrow) * KD + k0, lds_b + r0 * 32);
    }
    __syncthreads();
    bf16x8 af[4], bg[4];
#pragma unroll
    for (int i = 0; i < 4; ++i) {
      af[i] = *(const bf16x8*)(lds_a + (wm * 64 + i * 16 + ln) * 32 + qd * 8);
      bg[i] = *(const bf16x8*)(lds_b + (wn * 64 + i * 16 + ln) * 32 + qd * 8);
    }
#pragma unroll
    for (int i = 0; i < 4; ++i)
#pragma unroll
      for (int j = 0; j < 4; ++j)
        acc[i][j] = __builtin_amdgcn_mfma_f32_16x16x32_bf16(af[i], bg[j], acc[i][j], 0, 0, 0);
    __syncthreads();
  }
}

// ---- 1. convert x and W to bf16 ----
__global__ __launch_bounds__(256) void cvt_kernel(const float* __restrict__ x,
    const float* __restrict__ Wq, const float* __restrict__ Wk, const float* __restrict__ Wv,
    u16* __restrict__ xb, u16* __restrict__ Wb) {
  const int i = blockIdx.x * 256 + threadIdx.x;  // float4 index
  const int NX4 = (B_ * L_ * D_) / 4;            // 1,048,576
  f32x4 v;
  u16* dst;
  if (i < NX4) {
    v = ((const f32x4*)x)[i];
    dst = xb + (size_t)i * 4;
  } else {
    int wi = i - NX4;                 // 0..49151
    int z = wi >> 14;                 // which W (16384 f4 each)
    int off = wi & 16383;
    const float* W = (z == 0) ? Wq : (z == 1 ? Wk : Wv);
    v = ((const f32x4*)W)[off];
    dst = Wb + (size_t)z * 65536 + (size_t)off * 4;
  }
  unsigned p0 = (unsigned)f2b(v.x) | ((unsigned)f2b(v.y) << 16);
  unsigned p1 = (unsigned)f2b(v.z) | ((unsigned)f2b(v.w) << 16);
  *(uint2*)dst = make_uint2(p0, p1);
}

// ---- 2. QKV projection: y = x @ W^T + b ----
__global__ __launch_bounds__(256) void qkv_gemm(const u16* __restrict__ xb, const u16* __restrict__ Wb,
    const float* __restrict__ bq, const float* __restrict__ bk, const float* __restrict__ bv,
    u16* __restrict__ Qb, u16* __restrict__ Kb, u16* __restrict__ Vb,
    float* __restrict__ out_sp) {
  __shared__ u16 lds_a[128 * 32], lds_b[128 * 32];
  const int z = blockIdx.z;
  const float* bias = (z == 0) ? bq : (z == 1 ? bk : bv);
  u16* dst = (z == 0) ? Qb : (z == 1 ? Kb : Vb);
  const int tile_m = blockIdx.x * 128, tile_n = blockIdx.y * 128;
  f32x4 acc[4][4];
#pragma unroll
  for (int i = 0; i < 4; ++i)
#pragma unroll
    for (int j = 0; j < 4; ++j) acc[i][j] = (f32x4){0.f, 0.f, 0.f, 0.f};
  gemm_core<256>(xb, Wb + (size_t)z * 256 * 256, tile_m, tile_n, lds_a, lds_b, acc);

  const int lane = threadIdx.x & 63, wave = threadIdx.x >> 6;
  const int qd = lane >> 4, ln = lane & 15, wm = wave >> 1, wn = wave & 1;
#pragma unroll
  for (int i = 0; i < 4; ++i)
#pragma unroll
    for (int j = 0; j < 4; ++j) {
      const int col = tile_n + wn * 64 + j * 16 + ln;
      const float bvv = bias[col];
      const int row0 = tile_m + wm * 64 + i * 16 + qd * 4;
#pragma unroll
      for (int r = 0; r < 4; ++r) {
        const int row = row0 + r;
        const float val = acc[i][j][r] + bvv;
        dst[(size_t)row * D_ + col] = f2b(val);
        if (z == 0) {
          const int bb = row >> 11, l = row & 2047;
          out_sp[((size_t)bb * (2 * L_) + l) * D_ + col] = val;
        }
      }
    }
}

// ---- 3. transpose V (per batch [L,D] -> [D,L]) ----
__global__ __launch_bounds__(256) void transpose_v(const u16* __restrict__ Vb, u16* __restrict__ Vbt) {
  const int b = blockIdx.z;
  const int l0 = blockIdx.x * 64;
  const int d0 = blockIdx.y * 64;
  __shared__ u16 t[64][65];
  const int tx = threadIdx.x & 63;
  const int ty = threadIdx.x >> 6;
  const u16* src = Vb + (size_t)b * L_ * D_;
  for (int j = ty; j < 64; j += 4)
    t[j][tx] = src[(size_t)(l0 + j) * D_ + d0 + tx];
  __syncthreads();
  u16* dst = Vbt + (size_t)b * D_ * L_;
  for (int j = ty; j < 64; j += 4)
    dst[(size_t)(d0 + j) * L_ + l0 + tx] = t[tx][j];
}

// ---- 4. E = Q K^T / 16 -> bf16 ws, fused per-tile column-softmax partials ----
__global__ __launch_bounds__(256) void e_gemm(const u16* __restrict__ Qb, const u16* __restrict__ Kb,
                                              u16* __restrict__ Ebuf,
                                              float* __restrict__ pm, float* __restrict__ ps) {
  __shared__ u16 lds_a[128 * 32], lds_b[128 * 32];
  __shared__ float sm_m[4][64], sm_s[4][64];
  const int b = blockIdx.z;
  const int tile_m = blockIdx.x * 128, tile_n = blockIdx.y * 128;
  f32x4 acc[4][4];
#pragma unroll
  for (int i = 0; i < 4; ++i)
#pragma unroll
    for (int j = 0; j < 4; ++j) acc[i][j] = (f32x4){0.f, 0.f, 0.f, 0.f};
  gemm_core<256>(Qb + (size_t)b * L_ * D_, Kb + (size_t)b * L_ * D_, tile_m, tile_n, lds_a, lds_b, acc);

  u16* Eb = Ebuf + (size_t)b * L_ * L_;
  const int tid = threadIdx.x;
  const int lane = tid & 63, wave = tid >> 6;
  const int qd = lane >> 4, ln = lane & 15, wm = wave >> 1, wn = wave & 1;
#pragma unroll
  for (int j = 0; j < 4; ++j) {
    const int col = tile_n + wn * 64 + j * 16 + ln;
    const int row0 = tile_m + wm * 64 + qd * 4;
    float m = -1e30f;
#pragma unroll
    for (int i = 0; i < 4; ++i)
#pragma unroll
      for (int r = 0; r < 4; ++r)
        m = fmaxf(m, acc[i][j][r] * 0.0625f);
    float s = 0.f;
#pragma unroll
    for (int i = 0; i < 4; ++i)
#pragma unroll
      for (int r = 0; r < 4; ++r) {
        const float e = acc[i][j][r] * 0.0625f;
        Eb[(size_t)(row0 + i * 16 + r) * L_ + col] = f2b(e);
        s += __expf(e - m);
      }
    comb(m, s, __shfl_xor(m, 16), __shfl_xor(s, 16));
    comb(m, s, __shfl_xor(m, 32), __shfl_xor(s, 32));
    if (qd == 0) { sm_m[wave][j * 16 + ln] = m; sm_s[wave][j * 16 + ln] = s; }
  }
  __syncthreads();
  if (tid < 128) {
    const int w = tid >> 6, c = tid & 63;   // w = wn, columns wn*64 + c
    float m = sm_m[w][c], s = sm_s[w][c];
    comb(m, s, sm_m[w + 2][c], sm_s[w + 2][c]);
    const size_t idx = (size_t)blockIdx.x * (B_ * L_) + (size_t)b * L_ + tile_n + w * 64 + c;
    pm[idx] = m;
    ps[idx] = s;
  }
}

// ---- 5. reduce 16 tile partials -> rr = exp(-m)/s per (b,col) ----
__global__ __launch_bounds__(256) void stats_reduce(const float* __restrict__ pm,
                                                    const float* __restrict__ ps,
                                                    float* __restrict__ rrOut) {
  const int idx = blockIdx.x * 256 + threadIdx.x;  // 0..16383 = b*2048+col
  float m = -1e30f, s = 0.f;
#pragma unroll
  for (int t = 0; t < 16; ++t)
    comb(m, s, pm[t * (B_ * L_) + idx], ps[t * (B_ * L_) + idx]);
  rrOut[idx] = __expf(-m) / s;
}

// ---- 6. fused softmax-apply + A-write + A·V (barrier-free, LDS-free) ----
// grid (16 q-tiles, 4 = dsplit*2+ks, 8 batches); k-split halves -> C partials
__global__ __launch_bounds__(256) void av_fused(const u16* __restrict__ Eb16,
                                                const u16* __restrict__ Vbt,
                                                const float* __restrict__ rr,
                                                float* __restrict__ Aout,
                                                float* __restrict__ Cp) {
  const int b = blockIdx.z;
  const int tm = blockIdx.x * 128;
  const int dsplit = blockIdx.y >> 1, ks = blockIdx.y & 1;
  const int tile_n = dsplit * 128;
  const int tid = threadIdx.x, wave = tid >> 6, lane = tid & 63;
  const int qd = lane >> 4, ln = lane & 15, wm = wave >> 1, wn = wave & 1;
  const u16* Eb = Eb16 + (size_t)b * L_ * L_;
  const u16* Vt = Vbt + (size_t)b * D_ * L_;
  const float* rrb = rr + b * L_;
  float* Ab = Aout + (size_t)b * L_ * L_;
  const bool wA = (dsplit == 0) && (wn == 0);

  f32x4 acc[4][4];
#pragma unroll
  for (int i = 0; i < 4; ++i)
#pragma unroll
    for (int j = 0; j < 4; ++j) acc[i][j] = (f32x4){0.f, 0.f, 0.f, 0.f};

  const int arow0 = tm + wm * 64 + ln;       // + i*16
  const int brow0 = tile_n + wn * 64 + ln;   // + j*16
  const int k_begin = ks * (L_ / 2), k_end = k_begin + (L_ / 2);

  for (int k0 = k_begin; k0 < k_end; k0 += 32) {
    const int kk = k0 + qd * 8;
    float rv[8];
    *(f32x4*)rv       = *(const f32x4*)(rrb + kk);
    *(f32x4*)(rv + 4) = *(const f32x4*)(rrb + kk + 4);
    bf16x8 af[4], bg[4];
#pragma unroll
    for (int i = 0; i < 4; ++i) {
      bf16x8 raw = *(const bf16x8*)(Eb + (size_t)(arow0 + i * 16) * L_ + kk);
      bg[i] = *(const bf16x8*)(Vt + (size_t)(brow0 + i * 16) * L_ + kk);
      float a[8];
#pragma unroll
      for (int e = 0; e < 8; ++e)
        a[e] = __expf(b2f((u16)raw[e])) * rv[e];
      if (wA) {
        float* dst = Ab + (size_t)(arow0 + i * 16) * L_ + kk;
        *(f32x4*)dst       = (f32x4){a[0], a[1], a[2], a[3]};
        *(f32x4*)(dst + 4) = (f32x4){a[4], a[5], a[6], a[7]};
      }
      bf16x8 t;
#pragma unroll
      for (int e = 0; e < 8; ++e) t[e] = (short)f2b(a[e]);
      af[i] = t;
    }
#pragma unroll
    for (int i = 0; i < 4; ++i)
#pragma unroll
      for (int j = 0; j < 4; ++j)
        acc[i][j] = __builtin_amdgcn_mfma_f32_16x16x32_bf16(af[i], bg[j], acc[i][j], 0, 0, 0);
  }

  // write C partial: [b][tm][dsplit][ks][128q][128d]
  float* cp = Cp + ((((size_t)b * 16 + blockIdx.x) * 2 + dsplit) * 2 + ks) * (128 * 128);
#pragma unroll
  for (int i = 0; i < 4; ++i)
#pragma unroll
    for (int j = 0; j < 4; ++j) {
      const int row0 = wm * 64 + i * 16 + qd * 4;
      const int col = wn * 64 + j * 16 + ln;
#pragma unroll
      for (int r = 0; r < 4; ++r)
        cp[(size_t)(row0 + r) * 128 + col] = acc[i][j][r];
    }
}

// ---- 7. combine k-split C partials -> S_p second half ----
__global__ __launch_bounds__(256) void c_combine(const float* __restrict__ Cp,
                                                 float* __restrict__ out_sp) {
  const int t = blockIdx.x * 256 + threadIdx.x;   // 0..1,048,575 (f32x4 units)
  const int di4 = t & 31;
  int x = t >> 5;
  const int qi = x & 127; x >>= 7;
  const int ds = x & 1;   x >>= 1;
  const int tm = x & 15;
  const int b  = x >> 4;
  const size_t base = ((((size_t)b * 16 + tm) * 2 + ds) * 2) * (128 * 128)
                      + (size_t)qi * 128 + di4 * 4;
  f32x4 va = *(const f32x4*)(Cp + base);
  f32x4 vb = *(const f32x4*)(Cp + base + 128 * 128);
  const int q = tm * 128 + qi;
  const int d = ds * 128 + di4 * 4;
  *(f32x4*)(out_sp + ((size_t)b * (2 * L_) + L_ + q) * D_ + d) = va + vb;
}

extern "C" void kernel_launch(void* const* d_in, const int* in_sizes, int n_in,
                              void* d_out, int out_size, void* d_ws, size_t ws_size,
                              hipStream_t stream) {
  const float* x  = (const float*)d_in[0];
  const float* Wq = (const float*)d_in[1];
  const float* bq = (const float*)d_in[2];
  const float* Wk = (const float*)d_in[3];
  const float* bk = (const float*)d_in[4];
  const float* Wv = (const float*)d_in[5];
  const float* bv = (const float*)d_in[6];

  float* out  = (float*)d_out;                      // S_p: 8*4096*256 floats
  float* outA = out + (size_t)B_ * (2 * L_) * D_;   // A region: 8*2048*2048 floats

  // workspace layout (u16 elements)
  u16* w    = (u16*)d_ws;
  u16* xb   = w;                     // 4,194,304
  u16* Wb   = xb + 4194304;          //   196,608
  u16* Qb   = Wb + 196608;           // 4,194,304
  u16* Kb   = Qb + 4194304;          // 4,194,304
  u16* Vb   = Kb + 4194304;          // 4,194,304  (dead after transpose_v)
  u16* Vbt  = Vb + 4194304;          // 4,194,304
  u16* Eb16 = Vbt + 4194304;         // 33,554,432 (67 MB bf16 E)
  float* rrArr = (float*)(Eb16 + 33554432);   // 16,384
  float* pm    = rrArr + 16384;               // 262,144
  float* ps    = pm + 262144;                 // 262,144
  // C partials alias xb..Kb(+part of Vb), all dead by av_fused time:
  // needs 8,388,608 floats = 16,777,216 u16 < Vbt offset (16,973,824). Vbt safe.
  float* Cp = (float*)w;

  cvt_kernel<<<4288, 256, 0, stream>>>(x, Wq, Wk, Wv, xb, Wb);
  qkv_gemm<<<dim3(128, 2, 3), 256, 0, stream>>>(xb, Wb, bq, bk, bv, Qb, Kb, Vb, out);
  transpose_v<<<dim3(32, 4, 8), 256, 0, stream>>>(Vb, Vbt);
  e_gemm<<<dim3(16, 16, 8), 256, 0, stream>>>(Qb, Kb, Eb16, pm, ps);
  stats_reduce<<<64, 256, 0, stream>>>(pm, ps, rrArr);
  av_fused<<<dim3(16, 4, 8), 256, 0, stream>>>(Eb16, Vbt, rrArr, outA, Cp);
  c_combine<<<4096, 256, 0, stream>>>(Cp, out);
}